// Round 1
// baseline (1192.202 us; speedup 1.0000x reference)
//
#include <hip/hip_runtime.h>
#include <stdint.h>

// VGAE GCN encoder, fp32. Pipeline:
//   CSR build (hist -> scan -> fill) once; dinv = 1/sqrt(deg+1)
//   h1 = x@W1 (LDS-tiled vector GEMM)
//   a1 = relu(pull64(h1)+b1) ; h2 = a1@W2 ; a2 = relu(pull8(h2)+b2)
//   h3 = a2@W3 ; a3 = relu(pull4(h3)+b3) ; g = pull4(a3)
//   mu = g@Wmu+bmu ; lv = g@Wlv+blv   (linearity: scatter commutes with W)

// ---------------- CSR build ----------------
__global__ __launch_bounds__(256) void k_hist(const int* __restrict__ dst, int* __restrict__ cnt, int E) {
  int e = blockIdx.x * 256 + threadIdx.x;
  if (e < E) atomicAdd(&cnt[dst[e]], 1);
}

__global__ __launch_bounds__(1024) void k_scan1(const int* __restrict__ cnt, int* __restrict__ offs,
                                                int* __restrict__ bsum, float* __restrict__ dinv, int n) {
  int tid = threadIdx.x;
  int gid = blockIdx.x * 1024 + tid;
  int v = (gid < n) ? cnt[gid] : 0;
  if (gid < n) dinv[gid] = 1.0f / sqrtf((float)(v + 1));  // +1 self-loop
  int lane = tid & 63, wv = tid >> 6;
  int x = v;
#pragma unroll
  for (int d = 1; d < 64; d <<= 1) {
    int y = __shfl_up(x, d);
    if (lane >= d) x += y;
  }
  __shared__ int wsum[16];
  if (lane == 63) wsum[wv] = x;
  __syncthreads();
  if (tid < 16) {
    int s = wsum[tid];
#pragma unroll
    for (int d = 1; d < 16; d <<= 1) {
      int y = __shfl_up(s, d);
      if (tid >= d) s += y;
    }
    wsum[tid] = s;  // inclusive scan of wave totals
  }
  __syncthreads();
  int woff = wv ? wsum[wv - 1] : 0;
  if (gid < n) offs[gid] = woff + x - v;  // block-local exclusive
  if (tid == 0) bsum[blockIdx.x] = wsum[15];
}

__global__ __launch_bounds__(128) void k_scan2(int* __restrict__ bsum, int nb) {
  int tid = threadIdx.x;
  int v = (tid < nb) ? bsum[tid] : 0;
  int lane = tid & 63, wv = tid >> 6;
  int x = v;
#pragma unroll
  for (int d = 1; d < 64; d <<= 1) {
    int y = __shfl_up(x, d);
    if (lane >= d) x += y;
  }
  __shared__ int wsum[2];
  if (lane == 63) wsum[wv] = x;
  __syncthreads();
  int woff = wv ? wsum[0] : 0;
  if (tid < nb) bsum[tid] = woff + x - v;  // exclusive, in-place (reads done pre-barrier)
}

__global__ __launch_bounds__(1024) void k_scan3(int* __restrict__ offs, const int* __restrict__ bsum,
                                                int* __restrict__ cursor, int n, int E) {
  int gid = blockIdx.x * 1024 + threadIdx.x;
  if (gid < n) {
    int o = offs[gid] + bsum[blockIdx.x];
    offs[gid] = o;
    cursor[gid] = o;
  }
  if (gid == 0) offs[n] = E;
}

__global__ __launch_bounds__(256) void k_fill(const int* __restrict__ src, const int* __restrict__ dst,
                                              int* __restrict__ cursor, int* __restrict__ csr, int E) {
  int e = blockIdx.x * 256 + threadIdx.x;
  if (e < E) {
    int p = atomicAdd(&cursor[dst[e]], 1);
    csr[p] = src[e];
  }
}

// ---------------- GEMM1: h1[n][64] = x[n][512] @ W1[512][64] ----------------
// 128 threads = 128 nodes/block; acc[64]/thread; x tile in LDS (stride 33 pad),
// W k-tile in LDS, read as wave-uniform float4 broadcasts.
__global__ __launch_bounds__(128) void k_gemm1(const float* __restrict__ x, const float* __restrict__ W,
                                               float* __restrict__ h1, int n) {
  __shared__ float xs[128 * 33];
  __shared__ float wst[32 * 64];
  const int tid = threadIdx.x;
  const int n0 = blockIdx.x * 128;
  const int node = n0 + tid;

  float acc[64];
#pragma unroll
  for (int f = 0; f < 64; ++f) acc[f] = 0.f;

  const int xrow = tid >> 3;  // 0..15 (stride 16 over 8 iters -> 128 rows)
  const int xc4 = tid & 7;    // 0..7 -> col = xc4*4 (covers 32 cols)
  float4 px[8];
  float4 pw[4];
  // prefetch tile 0
  {
#pragma unroll
    for (int i = 0; i < 8; ++i) {
      int r = n0 + xrow + i * 16;
      if (r >= n) r = n - 1;
      px[i] = *(const float4*)(x + (size_t)r * 512 + xc4 * 4);
    }
    const float4* W4 = (const float4*)W;
#pragma unroll
    for (int i = 0; i < 4; ++i) pw[i] = W4[tid + 128 * i];
  }

  for (int t = 0; t < 16; ++t) {
    __syncthreads();
#pragma unroll
    for (int i = 0; i < 8; ++i) {
      float* d = &xs[(xrow + i * 16) * 33 + xc4 * 4];
      d[0] = px[i].x; d[1] = px[i].y; d[2] = px[i].z; d[3] = px[i].w;
    }
#pragma unroll
    for (int i = 0; i < 4; ++i) *(float4*)&wst[(tid + 128 * i) * 4] = pw[i];
    __syncthreads();
    if (t < 15) {  // prefetch next tile; latency hides under compute below
      int kt = (t + 1) * 32;
#pragma unroll
      for (int i = 0; i < 8; ++i) {
        int r = n0 + xrow + i * 16;
        if (r >= n) r = n - 1;
        px[i] = *(const float4*)(x + (size_t)r * 512 + kt + xc4 * 4);
      }
      const float4* W4 = (const float4*)(W + kt * 64);
#pragma unroll
      for (int i = 0; i < 4; ++i) pw[i] = W4[tid + 128 * i];
    }
#pragma unroll 4
    for (int k = 0; k < 32; ++k) {
      float xv = xs[tid * 33 + k];  // bank (tid+k)%32 -> conflict-free
      const float4* wr = (const float4*)&wst[k * 64];  // wave-uniform
#pragma unroll
      for (int f4 = 0; f4 < 16; ++f4) {
        float4 w = wr[f4];
        acc[f4 * 4 + 0] = fmaf(xv, w.x, acc[f4 * 4 + 0]);
        acc[f4 * 4 + 1] = fmaf(xv, w.y, acc[f4 * 4 + 1]);
        acc[f4 * 4 + 2] = fmaf(xv, w.z, acc[f4 * 4 + 2]);
        acc[f4 * 4 + 3] = fmaf(xv, w.w, acc[f4 * 4 + 3]);
      }
    }
  }
  if (node < n) {
    float4* o = (float4*)(h1 + (size_t)node * 64);
#pragma unroll
    for (int f4 = 0; f4 < 16; ++f4)
      o[f4] = make_float4(acc[f4 * 4], acc[f4 * 4 + 1], acc[f4 * 4 + 2], acc[f4 * 4 + 3]);
  }
}

// ---------------- pull kernels (CSR gather, normalized) ----------------
// out[i][f] = relu( dinv[i]*( sum_e dinv[s]*h[s][f] + dinv[i]*h[i][f] ) + b[f] )
__global__ __launch_bounds__(256) void k_pull64(const float* __restrict__ h, const int* __restrict__ offs,
                                                const int* __restrict__ csr, const float* __restrict__ dinv,
                                                const float* __restrict__ bias, float* __restrict__ out, int n) {
  int lane = threadIdx.x & 63;
  int node = blockIdx.x * 4 + (threadIdx.x >> 6);
  if (node >= n) return;
  int s0 = offs[node], s1 = offs[node + 1];
  float di = dinv[node];
  float acc = 0.f;
  int e = s0;
  for (; e + 4 <= s1; e += 4) {  // 4-wide unroll for memory-level parallelism
    int i0 = csr[e], i1 = csr[e + 1], i2 = csr[e + 2], i3 = csr[e + 3];
    float w0 = dinv[i0], w1 = dinv[i1], w2 = dinv[i2], w3 = dinv[i3];
    float v0 = h[i0 * 64 + lane], v1 = h[i1 * 64 + lane];
    float v2 = h[i2 * 64 + lane], v3 = h[i3 * 64 + lane];
    acc += w0 * v0; acc += w1 * v1; acc += w2 * v2; acc += w3 * v3;
  }
  for (; e < s1; ++e) {
    int s = csr[e];
    acc += dinv[s] * h[s * 64 + lane];
  }
  acc += di * h[node * 64 + lane];  // self-loop
  float o = fmaf(di, acc, bias[lane]);
  out[node * 64 + lane] = fmaxf(o, 0.f);
}

__global__ __launch_bounds__(256) void k_pull8(const float* __restrict__ h, const int* __restrict__ offs,
                                               const int* __restrict__ csr, const float* __restrict__ dinv,
                                               const float* __restrict__ bias, float* __restrict__ out, int n) {
  int lane = threadIdx.x & 63;
  int node = blockIdx.x * 4 + (threadIdx.x >> 6);
  if (node >= n) return;
  int j = lane >> 3, f = lane & 7;  // 8 edges x 8 features per iter
  int s0 = offs[node], s1 = offs[node + 1];
  float di = dinv[node];
  float pacc = 0.f;
  for (int e0 = s0; e0 < s1; e0 += 8) {
    int e = e0 + j;
    if (e < s1) {
      int s = csr[e];
      pacc += dinv[s] * h[s * 8 + f];
    }
  }
  pacc += __shfl_down(pacc, 32);
  pacc += __shfl_down(pacc, 16);
  pacc += __shfl_down(pacc, 8);
  if (lane < 8) {
    float v = pacc + di * h[node * 8 + f];
    out[node * 8 + f] = fmaxf(fmaf(di, v, bias[f]), 0.f);
  }
}

__global__ __launch_bounds__(256) void k_pull4(const float* __restrict__ h, const int* __restrict__ offs,
                                               const int* __restrict__ csr, const float* __restrict__ dinv,
                                               const float* __restrict__ bias, float* __restrict__ out, int n,
                                               int dorelu) {
  int lane = threadIdx.x & 63;
  int node = blockIdx.x * 4 + (threadIdx.x >> 6);
  if (node >= n) return;
  int j = lane >> 2, f = lane & 3;  // 16 edges x 4 features per iter
  int s0 = offs[node], s1 = offs[node + 1];
  float di = dinv[node];
  float pacc = 0.f;
  for (int e0 = s0; e0 < s1; e0 += 16) {
    int e = e0 + j;
    if (e < s1) {
      int s = csr[e];
      pacc += dinv[s] * h[s * 4 + f];
    }
  }
  pacc += __shfl_down(pacc, 32);
  pacc += __shfl_down(pacc, 16);
  pacc += __shfl_down(pacc, 8);
  pacc += __shfl_down(pacc, 4);
  if (lane < 4) {
    float v = pacc + di * h[node * 4 + f];
    float o = fmaf(di, v, bias ? bias[f] : 0.f);
    out[node * 4 + f] = dorelu ? fmaxf(o, 0.f) : o;
  }
}

// ---------------- small dense layers ----------------
__global__ __launch_bounds__(256) void k_gemm2(const float* __restrict__ a, const float* __restrict__ W,
                                               float* __restrict__ h, int n) {  // [N,64]@[64,8]
  int id = blockIdx.x * 256 + threadIdx.x;
  int node = id >> 3, f = id & 7;
  if (node >= n) return;
  const float4* ar4 = (const float4*)(a + node * 64);
  float acc = 0.f;
#pragma unroll
  for (int k4 = 0; k4 < 16; ++k4) {
    float4 av = ar4[k4];
    acc = fmaf(av.x, W[(k4 * 4 + 0) * 8 + f], acc);
    acc = fmaf(av.y, W[(k4 * 4 + 1) * 8 + f], acc);
    acc = fmaf(av.z, W[(k4 * 4 + 2) * 8 + f], acc);
    acc = fmaf(av.w, W[(k4 * 4 + 3) * 8 + f], acc);
  }
  h[node * 8 + f] = acc;
}

__global__ __launch_bounds__(256) void k_gemm3(const float* __restrict__ a, const float* __restrict__ W,
                                               float* __restrict__ h, int n) {  // [N,8]@[8,4]
  int id = blockIdx.x * 256 + threadIdx.x;
  int node = id >> 2, f = id & 3;
  if (node >= n) return;
  const float* ar = a + node * 8;
  float acc = 0.f;
#pragma unroll
  for (int k = 0; k < 8; ++k) acc = fmaf(ar[k], W[k * 4 + f], acc);
  h[node * 4 + f] = acc;
}

__global__ __launch_bounds__(256) void k_out(const float* __restrict__ g, const float* __restrict__ Wmu,
                                             const float* __restrict__ bmu, const float* __restrict__ Wlv,
                                             const float* __restrict__ blv, float* __restrict__ outp, int n) {
  int id = blockIdx.x * 256 + threadIdx.x;
  if (id >= n) return;
  float4 gv = *(const float4*)(g + (size_t)id * 4);
  float m0 = gv.x * Wmu[0] + gv.y * Wmu[2] + gv.z * Wmu[4] + gv.w * Wmu[6] + bmu[0];
  float m1 = gv.x * Wmu[1] + gv.y * Wmu[3] + gv.z * Wmu[5] + gv.w * Wmu[7] + bmu[1];
  float l0 = gv.x * Wlv[0] + gv.y * Wlv[2] + gv.z * Wlv[4] + gv.w * Wlv[6] + blv[0];
  float l1 = gv.x * Wlv[1] + gv.y * Wlv[3] + gv.z * Wlv[5] + gv.w * Wlv[7] + blv[1];
  ((float2*)outp)[id] = make_float2(m0, m1);
  ((float2*)(outp + (size_t)2 * n))[id] = make_float2(l0, l1);
}

extern "C" void kernel_launch(void* const* d_in, const int* in_sizes, int n_in,
                              void* d_out, int out_size, void* d_ws, size_t ws_size,
                              hipStream_t stream) {
  const float* x = (const float*)d_in[0];
  const int* ei = (const int*)d_in[1];
  const float* W1 = (const float*)d_in[2];
  const float* b1 = (const float*)d_in[3];
  const float* W2 = (const float*)d_in[4];
  const float* b2 = (const float*)d_in[5];
  const float* W3 = (const float*)d_in[6];
  const float* b3 = (const float*)d_in[7];
  const float* Wmu = (const float*)d_in[8];
  const float* bmu = (const float*)d_in[9];
  const float* Wlv = (const float*)d_in[10];
  const float* blv = (const float*)d_in[11];
  float* out = (float*)d_out;

  const int N = in_sizes[0] / 512;
  const int E = in_sizes[1] / 2;
  const int* esrc = ei;
  const int* edst = ei + E;

  char* w = (char*)d_ws;
  size_t p = 0;
  auto alloc = [&](size_t bytes) -> void* {
    void* r = w + p;
    p = (p + bytes + 255) & ~(size_t)255;
    return r;
  };
  int* cnt = (int*)alloc((size_t)N * 4);
  int* offs = (int*)alloc((size_t)(N + 1) * 4);
  int* cursor = (int*)alloc((size_t)N * 4);
  float* dinv = (float*)alloc((size_t)N * 4);
  int* bsum = (int*)alloc(1024);
  int* csr = (int*)alloc((size_t)E * 4);
  float* h1 = (float*)alloc((size_t)N * 64 * 4);
  float* a1 = (float*)alloc((size_t)N * 64 * 4);
  // later (narrow) buffers overlay h1's region -- h1 dead after k_pull64
  float* h2 = h1;
  float* a2 = h1 + (size_t)N * 8;
  float* h3 = h1 + (size_t)N * 16;
  float* a3 = h1 + (size_t)N * 20;
  float* g = h1 + (size_t)N * 24;

  hipMemsetAsync(cnt, 0, (size_t)N * 4, stream);
  k_hist<<<(E + 255) / 256, 256, 0, stream>>>(edst, cnt, E);
  int G1 = (N + 1023) / 1024;  // 98 (<=128 for k_scan2)
  k_scan1<<<G1, 1024, 0, stream>>>(cnt, offs, bsum, dinv, N);
  k_scan2<<<1, 128, 0, stream>>>(bsum, G1);
  k_scan3<<<G1, 1024, 0, stream>>>(offs, bsum, cursor, N, E);
  k_fill<<<(E + 255) / 256, 256, 0, stream>>>(esrc, edst, cursor, csr, E);

  k_gemm1<<<(N + 127) / 128, 128, 0, stream>>>(x, W1, h1, N);
  k_pull64<<<(N + 3) / 4, 256, 0, stream>>>(h1, offs, csr, dinv, b1, a1, N);
  k_gemm2<<<((size_t)N * 8 + 255) / 256, 256, 0, stream>>>(a1, W2, h2, N);
  k_pull8<<<(N + 3) / 4, 256, 0, stream>>>(h2, offs, csr, dinv, b2, a2, N);
  k_gemm3<<<((size_t)N * 4 + 255) / 256, 256, 0, stream>>>(a2, W3, h3, N);
  k_pull4<<<(N + 3) / 4, 256, 0, stream>>>(h3, offs, csr, dinv, b3, a3, N, 1);
  k_pull4<<<(N + 3) / 4, 256, 0, stream>>>(a3, offs, csr, dinv, nullptr, g, N, 0);
  k_out<<<(N + 255) / 256, 256, 0, stream>>>(g, Wmu, bmu, Wlv, blv, out, N);
}

// Round 2
// 1005.172 us; speedup vs baseline: 1.1861x; 1.1861x over previous
//
#include <hip/hip_runtime.h>
#include <hip/hip_fp16.h>
#include <stdint.h>

// VGAE GCN encoder, fp32 compute, fp16 h1 gather storage. Pipeline:
//   CSR build (hist -> scan -> fill) once; dinv = 1/sqrt(deg+1)
//   h1 = x@W1 (register-blocked LDS GEMM, fp16 out)
//   h2 = relu(pull64(h1)+b1) @ W2   (fused epilogue)
//   h3 = relu(pull8(h2)+b2) @ W3    (fused epilogue)
//   a3 = relu(pull4(h3)+b3)
//   [mu|lv] = pull4(a3) @ [Wmu|Wlv] + bias  (fused epilogue; pull commutes with W)

// ---------------- CSR build ----------------
__global__ __launch_bounds__(256) void k_hist(const int* __restrict__ dst, int* __restrict__ cnt, int E) {
  int e = blockIdx.x * 256 + threadIdx.x;
  if (e < E) atomicAdd(&cnt[dst[e]], 1);
}

__global__ __launch_bounds__(1024) void k_scan1(const int* __restrict__ cnt, int* __restrict__ offs,
                                                int* __restrict__ bsum, float* __restrict__ dinv, int n) {
  int tid = threadIdx.x;
  int gid = blockIdx.x * 1024 + tid;
  int v = (gid < n) ? cnt[gid] : 0;
  if (gid < n) dinv[gid] = 1.0f / sqrtf((float)(v + 1));  // +1 self-loop
  int lane = tid & 63, wv = tid >> 6;
  int x = v;
#pragma unroll
  for (int d = 1; d < 64; d <<= 1) {
    int y = __shfl_up(x, d);
    if (lane >= d) x += y;
  }
  __shared__ int wsum[16];
  if (lane == 63) wsum[wv] = x;
  __syncthreads();
  if (tid < 16) {
    int s = wsum[tid];
#pragma unroll
    for (int d = 1; d < 16; d <<= 1) {
      int y = __shfl_up(s, d);
      if (tid >= d) s += y;
    }
    wsum[tid] = s;  // inclusive scan of wave totals
  }
  __syncthreads();
  int woff = wv ? wsum[wv - 1] : 0;
  if (gid < n) offs[gid] = woff + x - v;  // block-local exclusive
  if (tid == 0) bsum[blockIdx.x] = wsum[15];
}

__global__ __launch_bounds__(128) void k_scan2(int* __restrict__ bsum, int nb) {
  int tid = threadIdx.x;
  int v = (tid < nb) ? bsum[tid] : 0;
  int lane = tid & 63, wv = tid >> 6;
  int x = v;
#pragma unroll
  for (int d = 1; d < 64; d <<= 1) {
    int y = __shfl_up(x, d);
    if (lane >= d) x += y;
  }
  __shared__ int wsum[2];
  if (lane == 63) wsum[wv] = x;
  __syncthreads();
  int woff = wv ? wsum[0] : 0;
  if (tid < nb) bsum[tid] = woff + x - v;  // exclusive, in-place
}

__global__ __launch_bounds__(1024) void k_scan3(int* __restrict__ offs, const int* __restrict__ bsum,
                                                int* __restrict__ cursor, int n, int E) {
  int gid = blockIdx.x * 1024 + threadIdx.x;
  if (gid < n) {
    int o = offs[gid] + bsum[blockIdx.x];
    offs[gid] = o;
    cursor[gid] = o;
  }
  if (gid == 0) offs[n] = E;
}

__global__ __launch_bounds__(256) void k_fill(const int* __restrict__ src, const int* __restrict__ dst,
                                              int* __restrict__ cursor, int* __restrict__ csr, int E) {
  int e = blockIdx.x * 256 + threadIdx.x;
  if (e < E) {
    int p = atomicAdd(&cursor[dst[e]], 1);
    csr[p] = src[e];
  }
}

// ---------------- GEMM1: h1[n][64] = x[n][512] @ W1[512][64], fp16 out --------
// 256 threads = 128 nodes x 64 feats per block; thread: 4 nodes x 8 feats (acc[32]).
// x tile transposed in LDS (xs[k][node], stride 132) -> 4-node ds_read_b128.
// W k-tile in LDS, near-broadcast b128 reads. Register double-buffer prefetch.
__global__ __launch_bounds__(256) void k_gemm1(const float* __restrict__ x, const float* __restrict__ W,
                                               __half* __restrict__ h1, int n) {
  __shared__ float xs[32 * 132];  // xs[k][node], pad to 132
  __shared__ float ws[32 * 64];   // ws[k][f]
  const int tid = threadIdx.x;
  const int n0 = blockIdx.x * 128;

  const int tn = tid & 31;  // nodes tn*4 .. tn*4+3
  const int tf = tid >> 5;  // feats tf*8 .. tf*8+7

  // x loader: rows lr+32i (i=0..3), k-cols lc*4..+3  (8 lanes span 128B row seg)
  const int lr = tid >> 3;  // 0..31
  const int lc = tid & 7;   // 0..7

  float4 px[4], pw[2];
  auto ldg_tile = [&](int kt) {
#pragma unroll
    for (int i = 0; i < 4; ++i) {
      int r = n0 + lr + i * 32;
      if (r >= n) r = n - 1;
      px[i] = *(const float4*)(x + (size_t)r * 512 + kt + lc * 4);
    }
#pragma unroll
    for (int i = 0; i < 2; ++i) {
      int idx = tid + 256 * i;
      int k = idx >> 4, f4 = idx & 15;
      pw[i] = *(const float4*)(W + (size_t)(kt + k) * 64 + f4 * 4);
    }
  };

  float acc[4][8];
#pragma unroll
  for (int i = 0; i < 4; ++i)
#pragma unroll
    for (int j = 0; j < 8; ++j) acc[i][j] = 0.f;

  ldg_tile(0);
  for (int t = 0; t < 16; ++t) {
    __syncthreads();
#pragma unroll
    for (int i = 0; i < 4; ++i) {
      int r = lr + i * 32;
      xs[(lc * 4 + 0) * 132 + r] = px[i].x;
      xs[(lc * 4 + 1) * 132 + r] = px[i].y;
      xs[(lc * 4 + 2) * 132 + r] = px[i].z;
      xs[(lc * 4 + 3) * 132 + r] = px[i].w;
    }
#pragma unroll
    for (int i = 0; i < 2; ++i) {
      int idx = tid + 256 * i;
      *(float4*)&ws[(idx >> 4) * 64 + (idx & 15) * 4] = pw[i];
    }
    __syncthreads();
    if (t < 15) ldg_tile((t + 1) * 32);  // prefetch hides under MACs below
#pragma unroll 8
    for (int k = 0; k < 32; ++k) {
      float4 xv = *(const float4*)&xs[k * 132 + tn * 4];
      float4 w0 = *(const float4*)&ws[k * 64 + tf * 8];
      float4 w1 = *(const float4*)&ws[k * 64 + tf * 8 + 4];
      float xa[4] = {xv.x, xv.y, xv.z, xv.w};
      float wb[8] = {w0.x, w0.y, w0.z, w0.w, w1.x, w1.y, w1.z, w1.w};
#pragma unroll
      for (int i = 0; i < 4; ++i)
#pragma unroll
        for (int j = 0; j < 8; ++j) acc[i][j] = fmaf(xa[i], wb[j], acc[i][j]);
    }
  }
#pragma unroll
  for (int i = 0; i < 4; ++i) {
    int node = n0 + tn * 4 + i;
    if (node < n) {
      union { int4 v; __half h[8]; } u;
#pragma unroll
      for (int j = 0; j < 8; ++j) u.h[j] = __float2half_rn(acc[i][j]);
      *(int4*)(h1 + (size_t)node * 64 + tf * 8) = u.v;
    }
  }
}

// ---------------- pull64 (fp16 gather) + fused gemm2 ----------------
// h2[i][:] = ( relu( dinv_i*(sum_e dinv_s*h1[s] + dinv_i*h1[i]) + b1 ) ) @ W2
__global__ __launch_bounds__(256) void k_pull64(const __half* __restrict__ h, const int* __restrict__ offs,
                                                const int* __restrict__ csr, const float* __restrict__ dinv,
                                                const float* __restrict__ b1, const float* __restrict__ W2,
                                                float* __restrict__ h2, int n) {
  __shared__ float sa[4][64];
  __shared__ float w2s[512];
  const int tid = threadIdx.x;
  w2s[tid] = W2[tid];
  w2s[tid + 256] = W2[tid + 256];
  const int lane = tid & 63;
  const int wv = tid >> 6;
  const int node = blockIdx.x * 4 + wv;
  float a1v = 0.f;
  if (node < n) {
    int s0 = offs[node], s1 = offs[node + 1];
    float di = dinv[node];
    float acc = 0.f;
    int e = s0;
    for (; e + 4 <= s1; e += 4) {  // MLP: 4 independent gathers in flight
      int i0 = csr[e], i1 = csr[e + 1], i2 = csr[e + 2], i3 = csr[e + 3];
      float w0 = dinv[i0], w1 = dinv[i1], w2 = dinv[i2], w3 = dinv[i3];
      float v0 = __half2float(h[(size_t)i0 * 64 + lane]);
      float v1 = __half2float(h[(size_t)i1 * 64 + lane]);
      float v2 = __half2float(h[(size_t)i2 * 64 + lane]);
      float v3 = __half2float(h[(size_t)i3 * 64 + lane]);
      acc = fmaf(w0, v0, acc); acc = fmaf(w1, v1, acc);
      acc = fmaf(w2, v2, acc); acc = fmaf(w3, v3, acc);
    }
    for (; e < s1; ++e) {
      int s = csr[e];
      acc = fmaf(dinv[s], __half2float(h[(size_t)s * 64 + lane]), acc);
    }
    acc = fmaf(di, __half2float(h[(size_t)node * 64 + lane]), acc);  // self-loop
    a1v = fmaxf(fmaf(di, acc, b1[lane]), 0.f);
  }
  sa[wv][lane] = a1v;
  __syncthreads();
  if (tid < 32) {
    int j = tid >> 3, f = tid & 7;
    int nd = blockIdx.x * 4 + j;
    if (nd < n) {
      float s = 0.f;
#pragma unroll
      for (int l = 0; l < 64; ++l) s = fmaf(sa[j][l], w2s[l * 8 + f], s);
      h2[(size_t)nd * 8 + f] = s;
    }
  }
}

// ---------------- pull8 + fused gemm3 ----------------
__global__ __launch_bounds__(256) void k_pull8(const float* __restrict__ h, const int* __restrict__ offs,
                                               const int* __restrict__ csr, const float* __restrict__ dinv,
                                               const float* __restrict__ b2, const float* __restrict__ W3,
                                               float* __restrict__ h3, int n) {
  __shared__ float sa[4][8];
  __shared__ float w3s[32];
  const int tid = threadIdx.x;
  if (tid < 32) w3s[tid] = W3[tid];
  const int lane = tid & 63;
  const int wv = tid >> 6;
  const int node = blockIdx.x * 4 + wv;
  const int j8 = lane >> 3, f = lane & 7;  // 8 edges x 8 feats per iter
  float pacc = 0.f;
  float di = 0.f;
  if (node < n) {
    int s0 = offs[node], s1 = offs[node + 1];
    di = dinv[node];
    for (int e0 = s0; e0 < s1; e0 += 8) {
      int e = e0 + j8;
      if (e < s1) {
        int s = csr[e];
        pacc = fmaf(dinv[s], h[(size_t)s * 8 + f], pacc);
      }
    }
  }
  pacc += __shfl_down(pacc, 32);
  pacc += __shfl_down(pacc, 16);
  pacc += __shfl_down(pacc, 8);
  if (node < n && lane < 8) {
    float v = pacc + di * h[(size_t)node * 8 + f];
    sa[wv][f] = fmaxf(fmaf(di, v, b2[f]), 0.f);
  }
  __syncthreads();
  if (tid < 16) {
    int j = tid >> 2, ff = tid & 3;
    int nd = blockIdx.x * 4 + j;
    if (nd < n) {
      float s = 0.f;
#pragma unroll
      for (int k = 0; k < 8; ++k) s = fmaf(sa[j][k], w3s[k * 4 + ff], s);
      h3[(size_t)nd * 4 + ff] = s;
    }
  }
}

// ---------------- pull4 (h3 -> a3, relu+bias) ----------------
__global__ __launch_bounds__(256) void k_pull4(const float* __restrict__ h, const int* __restrict__ offs,
                                               const int* __restrict__ csr, const float* __restrict__ dinv,
                                               const float* __restrict__ b3, float* __restrict__ out, int n) {
  const int tid = threadIdx.x;
  const int lane = tid & 63;
  const int node = blockIdx.x * 4 + (tid >> 6);
  if (node >= n) return;
  const int j16 = lane >> 2, f = lane & 3;  // 16 edges x 4 feats per iter
  int s0 = offs[node], s1 = offs[node + 1];
  float di = dinv[node];
  float pacc = 0.f;
  for (int e0 = s0; e0 < s1; e0 += 16) {
    int e = e0 + j16;
    if (e < s1) {
      int s = csr[e];
      pacc = fmaf(dinv[s], h[(size_t)s * 4 + f], pacc);
    }
  }
  pacc += __shfl_down(pacc, 32);
  pacc += __shfl_down(pacc, 16);
  pacc += __shfl_down(pacc, 8);
  pacc += __shfl_down(pacc, 4);
  if (lane < 4) {
    float v = pacc + di * h[(size_t)node * 4 + f];
    out[(size_t)node * 4 + f] = fmaxf(fmaf(di, v, b3[f]), 0.f);
  }
}

// ---------------- final pull4 + fused mu/lv heads ----------------
__global__ __launch_bounds__(256) void k_pull4o(const float* __restrict__ a3, const int* __restrict__ offs,
                                                const int* __restrict__ csr, const float* __restrict__ dinv,
                                                const float* __restrict__ Wmu, const float* __restrict__ bmu,
                                                const float* __restrict__ Wlv, const float* __restrict__ blv,
                                                float* __restrict__ outp, int n) {
  __shared__ float sg[4][4];
  const int tid = threadIdx.x;
  const int lane = tid & 63;
  const int wv = tid >> 6;
  const int node = blockIdx.x * 4 + wv;
  const int j16 = lane >> 2, f = lane & 3;
  float pacc = 0.f;
  float di = 0.f;
  if (node < n) {
    int s0 = offs[node], s1 = offs[node + 1];
    di = dinv[node];
    for (int e0 = s0; e0 < s1; e0 += 16) {
      int e = e0 + j16;
      if (e < s1) {
        int s = csr[e];
        pacc = fmaf(dinv[s], a3[(size_t)s * 4 + f], pacc);
      }
    }
  }
  pacc += __shfl_down(pacc, 32);
  pacc += __shfl_down(pacc, 16);
  pacc += __shfl_down(pacc, 8);
  pacc += __shfl_down(pacc, 4);
  if (node < n && lane < 4) {
    float v = pacc + di * a3[(size_t)node * 4 + f];
    sg[wv][f] = di * v;  // g (no bias, no relu here)
  }
  __syncthreads();
  if (tid < 16) {
    int j = tid >> 2, c = tid & 3;  // c: 0=mu0 1=mu1 2=lv0 3=lv1
    int nd = blockIdx.x * 4 + j;
    if (nd < n) {
      const float* Wp = (c < 2) ? Wmu : Wlv;
      const float* bp = (c < 2) ? bmu : blv;
      int cc = c & 1;
      float s = bp[cc];
#pragma unroll
      for (int k = 0; k < 4; ++k) s = fmaf(sg[j][k], Wp[k * 2 + cc], s);
      size_t base = (c < 2) ? 0 : (size_t)2 * n;
      outp[base + (size_t)nd * 2 + cc] = s;
    }
  }
}

extern "C" void kernel_launch(void* const* d_in, const int* in_sizes, int n_in,
                              void* d_out, int out_size, void* d_ws, size_t ws_size,
                              hipStream_t stream) {
  const float* x = (const float*)d_in[0];
  const int* ei = (const int*)d_in[1];
  const float* W1 = (const float*)d_in[2];
  const float* b1 = (const float*)d_in[3];
  const float* W2 = (const float*)d_in[4];
  const float* b2 = (const float*)d_in[5];
  const float* W3 = (const float*)d_in[6];
  const float* b3 = (const float*)d_in[7];
  const float* Wmu = (const float*)d_in[8];
  const float* bmu = (const float*)d_in[9];
  const float* Wlv = (const float*)d_in[10];
  const float* blv = (const float*)d_in[11];
  float* out = (float*)d_out;

  const int N = in_sizes[0] / 512;
  const int E = in_sizes[1] / 2;
  const int* esrc = ei;
  const int* edst = ei + E;

  char* w = (char*)d_ws;
  size_t p = 0;
  auto alloc = [&](size_t bytes) -> void* {
    void* r = w + p;
    p = (p + bytes + 255) & ~(size_t)255;
    return r;
  };
  int* cnt = (int*)alloc((size_t)N * 4);
  int* offs = (int*)alloc((size_t)(N + 1) * 4);
  int* cursor = (int*)alloc((size_t)N * 4);
  float* dinv = (float*)alloc((size_t)N * 4);
  int* bsum = (int*)alloc(1024);
  int* csr = (int*)alloc((size_t)E * 4);
  __half* h1 = (__half*)alloc((size_t)N * 64 * 2);
  float* h2 = (float*)alloc((size_t)N * 8 * 4);
  float* h3 = (float*)alloc((size_t)N * 4 * 4);
  float* a3 = (float*)alloc((size_t)N * 4 * 4);

  hipMemsetAsync(cnt, 0, (size_t)N * 4, stream);
  k_hist<<<(E + 255) / 256, 256, 0, stream>>>(edst, cnt, E);
  int G1 = (N + 1023) / 1024;  // 98 (<=128 for k_scan2)
  k_scan1<<<G1, 1024, 0, stream>>>(cnt, offs, bsum, dinv, N);
  k_scan2<<<1, 128, 0, stream>>>(bsum, G1);
  k_scan3<<<G1, 1024, 0, stream>>>(offs, bsum, cursor, N, E);
  k_fill<<<(E + 255) / 256, 256, 0, stream>>>(esrc, edst, cursor, csr, E);

  k_gemm1<<<(N + 127) / 128, 256, 0, stream>>>(x, W1, h1, N);
  k_pull64<<<(N + 3) / 4, 256, 0, stream>>>(h1, offs, csr, dinv, b1, W2, h2, N);
  k_pull8<<<(N + 3) / 4, 256, 0, stream>>>(h2, offs, csr, dinv, b2, W3, h3, N);
  k_pull4<<<(N + 3) / 4, 256, 0, stream>>>(h3, offs, csr, dinv, b3, a3, N);
  k_pull4o<<<(N + 3) / 4, 256, 0, stream>>>(a3, offs, csr, dinv, Wmu, bmu, Wlv, blv, out, N);
}

// Round 3
// 705.403 us; speedup vs baseline: 1.6901x; 1.4250x over previous
//
#include <hip/hip_runtime.h>
#include <hip/hip_fp16.h>
#include <stdint.h>

// VGAE GCN encoder. CSR build via 2-phase bucket partition (no random scatter):
//   P1 (fused w/ gemm1): edges -> 782 buckets of 128 dst-nodes, packed (src<<7)|dloc.
//       Monotone per-bucket cursors => writes cluster at line frontiers (L2-coalesced).
//   bscan: 782-entry exclusive scan -> bucket bases; offs[N]=E.
//   P2: per bucket: LDS degree count (replaces hist+scans, emits offs+dinv),
//       LDS rank + staged csr slice, coalesced copy-out.
// Then: h2 = relu(pull64(h1)+b1)@W2 ; h3 = relu(pull8(h2)+b2)@W3 ;
//       a3 = relu(pull4(h3)+b3) ; [mu|lv] = pull4(a3)@[Wmu|Wlv]+bias.

#define BSHIFT 7
#define BPB 128           // nodes per bucket
#define CAP 5632          // slots per bucket (avg 4096, sigma 64 -> 24 sigma margin)

// ---------------- fused gemm1 + partition ----------------
// gemm1: h1[n][64] = x[n][512] @ W1[512][64], fp16 out.
// 256 thr = 128 nodes x 64 feats; thread: 4 nodes x 8 feats (acc[32]).
__global__ __launch_bounds__(256) void k_gp(const float* __restrict__ x, const float* __restrict__ W,
                                            __half* __restrict__ h1, int n, int Gg,
                                            const int* __restrict__ esrc, const int* __restrict__ edst,
                                            int* __restrict__ bcnt, int* __restrict__ pairs, int E) {
  __shared__ float xs[32 * 132];  // xs[k][node], pad 132
  __shared__ float ws[32 * 64];   // ws[k][f]
  const int tid = threadIdx.x;

  if (blockIdx.x >= Gg) {
    // ---- partition path ----
    int e = (blockIdx.x - Gg) * 256 + tid;
    if (e < E) {
      int d = edst[e];
      int s = esrc[e];
      int b = d >> BSHIFT;
      int p = atomicAdd(&bcnt[b * 16], 1);  // 64B-padded counters
      pairs[(size_t)b * CAP + p] = (s << BSHIFT) | (d & (BPB - 1));
    }
    return;
  }

  // ---- gemm1 path ----
  const int n0 = blockIdx.x * 128;
  const int tn = tid & 31;  // nodes tn*4 .. +3
  const int tf = tid >> 5;  // feats tf*8 .. +7
  const int lr = tid >> 3;  // 0..31
  const int lc = tid & 7;   // 0..7

  float4 px[4], pw[2];
  auto ldg_tile = [&](int kt) {
#pragma unroll
    for (int i = 0; i < 4; ++i) {
      int r = n0 + lr + i * 32;
      if (r >= n) r = n - 1;
      px[i] = *(const float4*)(x + (size_t)r * 512 + kt + lc * 4);
    }
#pragma unroll
    for (int i = 0; i < 2; ++i) {
      int idx = tid + 256 * i;
      int k = idx >> 4, f4 = idx & 15;
      pw[i] = *(const float4*)(W + (size_t)(kt + k) * 64 + f4 * 4);
    }
  };

  float acc[4][8];
#pragma unroll
  for (int i = 0; i < 4; ++i)
#pragma unroll
    for (int j = 0; j < 8; ++j) acc[i][j] = 0.f;

  ldg_tile(0);
  for (int t = 0; t < 16; ++t) {
    __syncthreads();
#pragma unroll
    for (int i = 0; i < 4; ++i) {
      int r = lr + i * 32;
      xs[(lc * 4 + 0) * 132 + r] = px[i].x;
      xs[(lc * 4 + 1) * 132 + r] = px[i].y;
      xs[(lc * 4 + 2) * 132 + r] = px[i].z;
      xs[(lc * 4 + 3) * 132 + r] = px[i].w;
    }
#pragma unroll
    for (int i = 0; i < 2; ++i) {
      int idx = tid + 256 * i;
      *(float4*)&ws[(idx >> 4) * 64 + (idx & 15) * 4] = pw[i];
    }
    __syncthreads();
    if (t < 15) ldg_tile((t + 1) * 32);  // prefetch hides under MACs
#pragma unroll 8
    for (int k = 0; k < 32; ++k) {
      float4 xv = *(const float4*)&xs[k * 132 + tn * 4];
      float4 w0 = *(const float4*)&ws[k * 64 + tf * 8];
      float4 w1 = *(const float4*)&ws[k * 64 + tf * 8 + 4];
      float xa[4] = {xv.x, xv.y, xv.z, xv.w};
      float wb[8] = {w0.x, w0.y, w0.z, w0.w, w1.x, w1.y, w1.z, w1.w};
#pragma unroll
      for (int i = 0; i < 4; ++i)
#pragma unroll
        for (int j = 0; j < 8; ++j) acc[i][j] = fmaf(xa[i], wb[j], acc[i][j]);
    }
  }
#pragma unroll
  for (int i = 0; i < 4; ++i) {
    int node = n0 + tn * 4 + i;
    if (node < n) {
      union { int4 v; __half h[8]; } u;
#pragma unroll
      for (int j = 0; j < 8; ++j) u.h[j] = __float2half_rn(acc[i][j]);
      *(int4*)(h1 + (size_t)node * 64 + tf * 8) = u.v;
    }
  }
}

// ---------------- bucket-size scan (one block) ----------------
__global__ __launch_bounds__(1024) void k_bscan(const int* __restrict__ bcnt, int* __restrict__ bbase,
                                                int* __restrict__ offs, int NB, int n, int E) {
  __shared__ int sc[1024];
  int tid = threadIdx.x;
  int v = (tid < NB) ? bcnt[tid * 16] : 0;
  sc[tid] = v;
  __syncthreads();
  for (int d = 1; d < 1024; d <<= 1) {
    int t = (tid >= d) ? sc[tid - d] : 0;
    __syncthreads();
    if (tid >= d) sc[tid] += t;
    __syncthreads();
  }
  if (tid < NB) bbase[tid] = sc[tid] - v;  // exclusive
  if (tid == 0) offs[n] = E;
}

// ---------------- per-bucket CSR finalize (also emits offs + dinv) -----------
__global__ __launch_bounds__(1024) void k_p2(const int* __restrict__ pairs, const int* __restrict__ bcnt,
                                             const int* __restrict__ bbase, int* __restrict__ offs,
                                             float* __restrict__ dinv, int* __restrict__ csr, int n) {
  __shared__ int lcnt[BPB];
  __shared__ int scanv[BPB];
  __shared__ int cur[BPB];
  __shared__ int sbuf[CAP];
  const int tid = threadIdx.x;
  const int b = blockIdx.x;
  const int size = bcnt[b * 16];
  const int base = bbase[b];
  const int node0 = b << BSHIFT;
  const int nb = min(BPB, n - node0);

  if (tid < BPB) lcnt[tid] = 0;
  __syncthreads();

  int stash[6];
  int ns = 0;
  for (int i = tid; i < size; i += 1024) {
    int w = pairs[(size_t)b * CAP + i];
    stash[ns++] = w;
    atomicAdd(&lcnt[w & (BPB - 1)], 1);
  }
  __syncthreads();
  if (tid < BPB) scanv[tid] = lcnt[tid];
  __syncthreads();
#pragma unroll
  for (int d = 1; d < BPB; d <<= 1) {
    int t = (tid < BPB && tid >= d) ? scanv[tid - d] : 0;
    __syncthreads();
    if (tid < BPB && tid >= d) scanv[tid] += t;
    __syncthreads();
  }
  if (tid < nb) {
    int excl = scanv[tid] - lcnt[tid];
    offs[node0 + tid] = base + excl;
    cur[tid] = excl;
    dinv[node0 + tid] = rsqrtf((float)(lcnt[tid] + 1));  // +1 self-loop
  }
  __syncthreads();
  for (int i = 0; i < ns; ++i) {
    int w = stash[i];
    int p = atomicAdd(&cur[w & (BPB - 1)], 1);
    sbuf[p] = w >> BSHIFT;
  }
  __syncthreads();
  for (int i = tid; i < size; i += 1024) csr[base + i] = sbuf[i];
}

// ---------------- pull64 (fp16 gather) + fused gemm2 ----------------
__global__ __launch_bounds__(256) void k_pull64(const __half* __restrict__ h, const int* __restrict__ offs,
                                                const int* __restrict__ csr, const float* __restrict__ dinv,
                                                const float* __restrict__ b1, const float* __restrict__ W2,
                                                float* __restrict__ h2, int n) {
  __shared__ float sa[4][64];
  __shared__ float w2s[512];
  const int tid = threadIdx.x;
  w2s[tid] = W2[tid];
  w2s[tid + 256] = W2[tid + 256];
  const int lane = tid & 63;
  const int wv = tid >> 6;
  const int node = blockIdx.x * 4 + wv;
  float a1v = 0.f;
  if (node < n) {
    int s0 = offs[node], s1 = offs[node + 1];
    float di = dinv[node];
    float acc = 0.f;
    int e = s0;
    for (; e + 4 <= s1; e += 4) {
      int i0 = csr[e], i1 = csr[e + 1], i2 = csr[e + 2], i3 = csr[e + 3];
      float w0 = dinv[i0], w1 = dinv[i1], w2 = dinv[i2], w3 = dinv[i3];
      float v0 = __half2float(h[(size_t)i0 * 64 + lane]);
      float v1 = __half2float(h[(size_t)i1 * 64 + lane]);
      float v2 = __half2float(h[(size_t)i2 * 64 + lane]);
      float v3 = __half2float(h[(size_t)i3 * 64 + lane]);
      acc = fmaf(w0, v0, acc); acc = fmaf(w1, v1, acc);
      acc = fmaf(w2, v2, acc); acc = fmaf(w3, v3, acc);
    }
    for (; e < s1; ++e) {
      int s = csr[e];
      acc = fmaf(dinv[s], __half2float(h[(size_t)s * 64 + lane]), acc);
    }
    acc = fmaf(di, __half2float(h[(size_t)node * 64 + lane]), acc);  // self-loop
    a1v = fmaxf(fmaf(di, acc, b1[lane]), 0.f);
  }
  sa[wv][lane] = a1v;
  __syncthreads();
  if (tid < 32) {
    int j = tid >> 3, f = tid & 7;
    int nd = blockIdx.x * 4 + j;
    if (nd < n) {
      float s = 0.f;
#pragma unroll
      for (int l = 0; l < 64; ++l) s = fmaf(sa[j][l], w2s[l * 8 + f], s);
      h2[(size_t)nd * 8 + f] = s;
    }
  }
}

// ---------------- pull8 + fused gemm3 ----------------
__global__ __launch_bounds__(256) void k_pull8(const float* __restrict__ h, const int* __restrict__ offs,
                                               const int* __restrict__ csr, const float* __restrict__ dinv,
                                               const float* __restrict__ b2, const float* __restrict__ W3,
                                               float* __restrict__ h3, int n) {
  __shared__ float sa[4][8];
  __shared__ float w3s[32];
  const int tid = threadIdx.x;
  if (tid < 32) w3s[tid] = W3[tid];
  const int lane = tid & 63;
  const int wv = tid >> 6;
  const int node = blockIdx.x * 4 + wv;
  const int j8 = lane >> 3, f = lane & 7;
  float pacc = 0.f;
  float di = 0.f;
  if (node < n) {
    int s0 = offs[node], s1 = offs[node + 1];
    di = dinv[node];
    for (int e0 = s0; e0 < s1; e0 += 8) {
      int e = e0 + j8;
      if (e < s1) {
        int s = csr[e];
        pacc = fmaf(dinv[s], h[(size_t)s * 8 + f], pacc);
      }
    }
  }
  pacc += __shfl_down(pacc, 32);
  pacc += __shfl_down(pacc, 16);
  pacc += __shfl_down(pacc, 8);
  if (node < n && lane < 8) {
    float v = pacc + di * h[(size_t)node * 8 + f];
    sa[wv][f] = fmaxf(fmaf(di, v, b2[f]), 0.f);
  }
  __syncthreads();
  if (tid < 16) {
    int j = tid >> 2, ff = tid & 3;
    int nd = blockIdx.x * 4 + j;
    if (nd < n) {
      float s = 0.f;
#pragma unroll
      for (int k = 0; k < 8; ++k) s = fmaf(sa[j][k], w3s[k * 4 + ff], s);
      h3[(size_t)nd * 4 + ff] = s;
    }
  }
}

// ---------------- pull4 (h3 -> a3, relu+bias) ----------------
__global__ __launch_bounds__(256) void k_pull4(const float* __restrict__ h, const int* __restrict__ offs,
                                               const int* __restrict__ csr, const float* __restrict__ dinv,
                                               const float* __restrict__ b3, float* __restrict__ out, int n) {
  const int tid = threadIdx.x;
  const int lane = tid & 63;
  const int node = blockIdx.x * 4 + (tid >> 6);
  if (node >= n) return;
  const int j16 = lane >> 2, f = lane & 3;
  int s0 = offs[node], s1 = offs[node + 1];
  float di = dinv[node];
  float pacc = 0.f;
  for (int e0 = s0; e0 < s1; e0 += 16) {
    int e = e0 + j16;
    if (e < s1) {
      int s = csr[e];
      pacc = fmaf(dinv[s], h[(size_t)s * 4 + f], pacc);
    }
  }
  pacc += __shfl_down(pacc, 32);
  pacc += __shfl_down(pacc, 16);
  pacc += __shfl_down(pacc, 8);
  pacc += __shfl_down(pacc, 4);
  if (lane < 4) {
    float v = pacc + di * h[(size_t)node * 4 + f];
    out[(size_t)node * 4 + f] = fmaxf(fmaf(di, v, b3[f]), 0.f);
  }
}

// ---------------- final pull4 + fused mu/lv heads ----------------
__global__ __launch_bounds__(256) void k_pull4o(const float* __restrict__ a3, const int* __restrict__ offs,
                                                const int* __restrict__ csr, const float* __restrict__ dinv,
                                                const float* __restrict__ Wmu, const float* __restrict__ bmu,
                                                const float* __restrict__ Wlv, const float* __restrict__ blv,
                                                float* __restrict__ outp, int n) {
  __shared__ float sg[4][4];
  const int tid = threadIdx.x;
  const int lane = tid & 63;
  const int wv = tid >> 6;
  const int node = blockIdx.x * 4 + wv;
  const int j16 = lane >> 2, f = lane & 3;
  float pacc = 0.f;
  float di = 0.f;
  if (node < n) {
    int s0 = offs[node], s1 = offs[node + 1];
    di = dinv[node];
    for (int e0 = s0; e0 < s1; e0 += 16) {
      int e = e0 + j16;
      if (e < s1) {
        int s = csr[e];
        pacc = fmaf(dinv[s], a3[(size_t)s * 4 + f], pacc);
      }
    }
  }
  pacc += __shfl_down(pacc, 32);
  pacc += __shfl_down(pacc, 16);
  pacc += __shfl_down(pacc, 8);
  pacc += __shfl_down(pacc, 4);
  if (node < n && lane < 4) {
    float v = pacc + di * a3[(size_t)node * 4 + f];
    sg[wv][f] = di * v;
  }
  __syncthreads();
  if (tid < 16) {
    int j = tid >> 2, c = tid & 3;  // c: 0=mu0 1=mu1 2=lv0 3=lv1
    int nd = blockIdx.x * 4 + j;
    if (nd < n) {
      const float* Wp = (c < 2) ? Wmu : Wlv;
      const float* bp = (c < 2) ? bmu : blv;
      int cc = c & 1;
      float s = bp[cc];
#pragma unroll
      for (int k = 0; k < 4; ++k) s = fmaf(sg[j][k], Wp[k * 2 + cc], s);
      size_t base = (c < 2) ? 0 : (size_t)2 * n;
      outp[base + (size_t)nd * 2 + cc] = s;
    }
  }
}

extern "C" void kernel_launch(void* const* d_in, const int* in_sizes, int n_in,
                              void* d_out, int out_size, void* d_ws, size_t ws_size,
                              hipStream_t stream) {
  const float* x = (const float*)d_in[0];
  const int* ei = (const int*)d_in[1];
  const float* W1 = (const float*)d_in[2];
  const float* b1 = (const float*)d_in[3];
  const float* W2 = (const float*)d_in[4];
  const float* b2 = (const float*)d_in[5];
  const float* W3 = (const float*)d_in[6];
  const float* b3 = (const float*)d_in[7];
  const float* Wmu = (const float*)d_in[8];
  const float* bmu = (const float*)d_in[9];
  const float* Wlv = (const float*)d_in[10];
  const float* blv = (const float*)d_in[11];
  float* out = (float*)d_out;

  const int N = in_sizes[0] / 512;
  const int E = in_sizes[1] / 2;
  const int* esrc = ei;
  const int* edst = ei + E;
  const int NB = (N + BPB - 1) >> BSHIFT;  // 782

  char* w = (char*)d_ws;
  size_t p = 0;
  auto alloc = [&](size_t bytes) -> void* {
    void* r = w + p;
    p = (p + bytes + 255) & ~(size_t)255;
    return r;
  };
  int* bcnt = (int*)alloc((size_t)NB * 16 * 4);  // 64B-padded counters
  int* bbase = (int*)alloc((size_t)NB * 4);
  int* offs = (int*)alloc((size_t)(N + 1) * 4);
  float* dinv = (float*)alloc((size_t)N * 4);
  int* csr = (int*)alloc((size_t)E * 4);
  int* pairs = (int*)alloc((size_t)NB * CAP * 4);
  __half* h1 = (__half*)alloc((size_t)N * 64 * 2);
  float* h2 = (float*)alloc((size_t)N * 8 * 4);
  float* h3 = (float*)alloc((size_t)N * 4 * 4);
  float* a3 = (float*)alloc((size_t)N * 4 * 4);

  hipMemsetAsync(bcnt, 0, (size_t)NB * 16 * 4, stream);

  const int Gg = (N + 127) / 128;
  const int Gp = (E + 255) / 256;
  k_gp<<<Gg + Gp, 256, 0, stream>>>(x, W1, h1, N, Gg, esrc, edst, bcnt, pairs, E);
  k_bscan<<<1, 1024, 0, stream>>>(bcnt, bbase, offs, NB, N, E);
  k_p2<<<NB, 1024, 0, stream>>>(pairs, bcnt, bbase, offs, dinv, csr, N);

  k_pull64<<<(N + 3) / 4, 256, 0, stream>>>(h1, offs, csr, dinv, b1, W2, h2, N);
  k_pull8<<<(N + 3) / 4, 256, 0, stream>>>(h2, offs, csr, dinv, b2, W3, h3, N);
  k_pull4<<<(N + 3) / 4, 256, 0, stream>>>(h3, offs, csr, dinv, b3, a3, N);
  k_pull4o<<<(N + 3) / 4, 256, 0, stream>>>(a3, offs, csr, dinv, Wmu, bmu, Wlv, blv, out, N);
}

// Round 4
// 698.154 us; speedup vs baseline: 1.7077x; 1.0104x over previous
//
#include <hip/hip_runtime.h>
#include <hip/hip_fp16.h>
#include <stdint.h>

// VGAE GCN encoder. CSR build via 2-phase bucket partition (no random scatter):
//   P1 (fused w/ gemm1): edges -> 782 buckets of 128 dst-nodes, packed (src<<7)|dloc.
//   bscan: 782-entry exclusive scan -> bucket bases; offs[N]=E.
//   P2: per bucket: LDS degree count (emits offs+dinv), LDS rank, coalesced csr out.
// Then: h2 = relu(pull64(h1)+b1)@W2 ; h3 = relu(pull8(h2)+b2)@W3 ;
//       a3 = relu(pull4(h3)+b3) ; [mu|lv] = pull4(a3)@[Wmu|Wlv]+bias.
//
// R3->R4: k_gp spilled (VGPR_Count=64 vs ~90 live; WRITE_SIZE 232MB vs 27MB legit).
//   Fix: __launch_bounds__(256,4) -> 128-VGPR cap, no spill.
//   xs stride 132->133: store bank = (20*lc+5*j+lr)%32 tiles 32 banks 2x -> free.

#define BSHIFT 7
#define BPB 128           // nodes per bucket
#define CAP 5632          // slots per bucket (avg 4096, sigma 64 -> 24 sigma margin)

// ---------------- fused gemm1 + partition ----------------
// gemm1: h1[n][64] = x[n][512] @ W1[512][64], fp16 out.
// 256 thr = 128 nodes x 64 feats; thread: 4 nodes x 8 feats (acc[32]).
__global__ __launch_bounds__(256, 4) void k_gp(const float* __restrict__ x, const float* __restrict__ W,
                                               __half* __restrict__ h1, int n, int Gg,
                                               const int* __restrict__ esrc, const int* __restrict__ edst,
                                               int* __restrict__ bcnt, int* __restrict__ pairs, int E) {
  __shared__ float xs[32 * 133];  // xs[k][node], pad 133 (bank-conflict-free stores)
  __shared__ float ws[32 * 64];   // ws[k][f]
  const int tid = threadIdx.x;

  if (blockIdx.x >= Gg) {
    // ---- partition path ----
    int e = (blockIdx.x - Gg) * 256 + tid;
    if (e < E) {
      int d = edst[e];
      int s = esrc[e];
      int b = d >> BSHIFT;
      int p = atomicAdd(&bcnt[b * 16], 1);  // 64B-padded counters
      pairs[(size_t)b * CAP + p] = (s << BSHIFT) | (d & (BPB - 1));
    }
    return;
  }

  // ---- gemm1 path ----
  const int n0 = blockIdx.x * 128;
  const int tn = tid & 31;  // nodes tn*4 .. +3
  const int tf = tid >> 5;  // feats tf*8 .. +7
  const int lr = tid >> 3;  // 0..31
  const int lc = tid & 7;   // 0..7

  float4 px[4], pw[2];
  auto ldg_tile = [&](int kt) {
#pragma unroll
    for (int i = 0; i < 4; ++i) {
      int r = n0 + lr + i * 32;
      if (r >= n) r = n - 1;
      px[i] = *(const float4*)(x + (size_t)r * 512 + kt + lc * 4);
    }
#pragma unroll
    for (int i = 0; i < 2; ++i) {
      int idx = tid + 256 * i;
      int k = idx >> 4, f4 = idx & 15;
      pw[i] = *(const float4*)(W + (size_t)(kt + k) * 64 + f4 * 4);
    }
  };

  float acc[4][8];
#pragma unroll
  for (int i = 0; i < 4; ++i)
#pragma unroll
    for (int j = 0; j < 8; ++j) acc[i][j] = 0.f;

  ldg_tile(0);
  for (int t = 0; t < 16; ++t) {
    __syncthreads();
#pragma unroll
    for (int i = 0; i < 4; ++i) {
      int r = lr + i * 32;
      xs[(lc * 4 + 0) * 133 + r] = px[i].x;
      xs[(lc * 4 + 1) * 133 + r] = px[i].y;
      xs[(lc * 4 + 2) * 133 + r] = px[i].z;
      xs[(lc * 4 + 3) * 133 + r] = px[i].w;
    }
#pragma unroll
    for (int i = 0; i < 2; ++i) {
      int idx = tid + 256 * i;
      *(float4*)&ws[(idx >> 4) * 64 + (idx & 15) * 4] = pw[i];
    }
    __syncthreads();
    if (t < 15) ldg_tile((t + 1) * 32);  // prefetch hides under MACs
#pragma unroll 8
    for (int k = 0; k < 32; ++k) {
      float4 xv = *(const float4*)&xs[k * 133 + tn * 4];
      float4 w0 = *(const float4*)&ws[k * 64 + tf * 8];
      float4 w1 = *(const float4*)&ws[k * 64 + tf * 8 + 4];
      float xa[4] = {xv.x, xv.y, xv.z, xv.w};
      float wb[8] = {w0.x, w0.y, w0.z, w0.w, w1.x, w1.y, w1.z, w1.w};
#pragma unroll
      for (int i = 0; i < 4; ++i)
#pragma unroll
        for (int j = 0; j < 8; ++j) acc[i][j] = fmaf(xa[i], wb[j], acc[i][j]);
    }
  }
#pragma unroll
  for (int i = 0; i < 4; ++i) {
    int node = n0 + tn * 4 + i;
    if (node < n) {
      union { int4 v; __half h[8]; } u;
#pragma unroll
      for (int j = 0; j < 8; ++j) u.h[j] = __float2half_rn(acc[i][j]);
      *(int4*)(h1 + (size_t)node * 64 + tf * 8) = u.v;
    }
  }
}

// ---------------- bucket-size scan (one block) ----------------
__global__ __launch_bounds__(1024) void k_bscan(const int* __restrict__ bcnt, int* __restrict__ bbase,
                                                int* __restrict__ offs, int NB, int n, int E) {
  __shared__ int sc[1024];
  int tid = threadIdx.x;
  int v = (tid < NB) ? bcnt[tid * 16] : 0;
  sc[tid] = v;
  __syncthreads();
  for (int d = 1; d < 1024; d <<= 1) {
    int t = (tid >= d) ? sc[tid - d] : 0;
    __syncthreads();
    if (tid >= d) sc[tid] += t;
    __syncthreads();
  }
  if (tid < NB) bbase[tid] = sc[tid] - v;  // exclusive
  if (tid == 0) offs[n] = E;
}

// ---------------- per-bucket CSR finalize (also emits offs + dinv) -----------
__global__ __launch_bounds__(1024) void k_p2(const int* __restrict__ pairs, const int* __restrict__ bcnt,
                                             const int* __restrict__ bbase, int* __restrict__ offs,
                                             float* __restrict__ dinv, int* __restrict__ csr, int n) {
  __shared__ int lcnt[BPB];
  __shared__ int scanv[BPB];
  __shared__ int cur[BPB];
  __shared__ int sbuf[CAP];
  const int tid = threadIdx.x;
  const int b = blockIdx.x;
  const int size = bcnt[b * 16];
  const int base = bbase[b];
  const int node0 = b << BSHIFT;
  const int nb = min(BPB, n - node0);

  if (tid < BPB) lcnt[tid] = 0;
  __syncthreads();

  int stash[6];
  int ns = 0;
  for (int i = tid; i < size; i += 1024) {
    int w = pairs[(size_t)b * CAP + i];
    stash[ns++] = w;
    atomicAdd(&lcnt[w & (BPB - 1)], 1);
  }
  __syncthreads();
  if (tid < BPB) scanv[tid] = lcnt[tid];
  __syncthreads();
#pragma unroll
  for (int d = 1; d < BPB; d <<= 1) {
    int t = (tid < BPB && tid >= d) ? scanv[tid - d] : 0;
    __syncthreads();
    if (tid < BPB && tid >= d) scanv[tid] += t;
    __syncthreads();
  }
  if (tid < nb) {
    int excl = scanv[tid] - lcnt[tid];
    offs[node0 + tid] = base + excl;
    cur[tid] = excl;
    dinv[node0 + tid] = rsqrtf((float)(lcnt[tid] + 1));  // +1 self-loop
  }
  __syncthreads();
  for (int i = 0; i < ns; ++i) {
    int w = stash[i];
    int p = atomicAdd(&cur[w & (BPB - 1)], 1);
    sbuf[p] = w >> BSHIFT;
  }
  __syncthreads();
  for (int i = tid; i < size; i += 1024) csr[base + i] = sbuf[i];
}

// ---------------- pull64 (fp16 gather) + fused gemm2 ----------------
__global__ __launch_bounds__(256) void k_pull64(const __half* __restrict__ h, const int* __restrict__ offs,
                                                const int* __restrict__ csr, const float* __restrict__ dinv,
                                                const float* __restrict__ b1, const float* __restrict__ W2,
                                                float* __restrict__ h2, int n) {
  __shared__ float sa[4][64];
  __shared__ float w2s[512];
  const int tid = threadIdx.x;
  w2s[tid] = W2[tid];
  w2s[tid + 256] = W2[tid + 256];
  const int lane = tid & 63;
  const int wv = tid >> 6;
  const int node = blockIdx.x * 4 + wv;
  float a1v = 0.f;
  if (node < n) {
    int s0 = offs[node], s1 = offs[node + 1];
    float di = dinv[node];
    float acc = 0.f;
    int e = s0;
    for (; e + 4 <= s1; e += 4) {
      int i0 = csr[e], i1 = csr[e + 1], i2 = csr[e + 2], i3 = csr[e + 3];
      float w0 = dinv[i0], w1 = dinv[i1], w2 = dinv[i2], w3 = dinv[i3];
      float v0 = __half2float(h[(size_t)i0 * 64 + lane]);
      float v1 = __half2float(h[(size_t)i1 * 64 + lane]);
      float v2 = __half2float(h[(size_t)i2 * 64 + lane]);
      float v3 = __half2float(h[(size_t)i3 * 64 + lane]);
      acc = fmaf(w0, v0, acc); acc = fmaf(w1, v1, acc);
      acc = fmaf(w2, v2, acc); acc = fmaf(w3, v3, acc);
    }
    for (; e < s1; ++e) {
      int s = csr[e];
      acc = fmaf(dinv[s], __half2float(h[(size_t)s * 64 + lane]), acc);
    }
    acc = fmaf(di, __half2float(h[(size_t)node * 64 + lane]), acc);  // self-loop
    a1v = fmaxf(fmaf(di, acc, b1[lane]), 0.f);
  }
  sa[wv][lane] = a1v;
  __syncthreads();
  if (tid < 32) {
    int j = tid >> 3, f = tid & 7;
    int nd = blockIdx.x * 4 + j;
    if (nd < n) {
      float s = 0.f;
#pragma unroll
      for (int l = 0; l < 64; ++l) s = fmaf(sa[j][l], w2s[l * 8 + f], s);
      h2[(size_t)nd * 8 + f] = s;
    }
  }
}

// ---------------- pull8 + fused gemm3 ----------------
__global__ __launch_bounds__(256) void k_pull8(const float* __restrict__ h, const int* __restrict__ offs,
                                               const int* __restrict__ csr, const float* __restrict__ dinv,
                                               const float* __restrict__ b2, const float* __restrict__ W3,
                                               float* __restrict__ h3, int n) {
  __shared__ float sa[4][8];
  __shared__ float w3s[32];
  const int tid = threadIdx.x;
  if (tid < 32) w3s[tid] = W3[tid];
  const int lane = tid & 63;
  const int wv = tid >> 6;
  const int node = blockIdx.x * 4 + wv;
  const int j8 = lane >> 3, f = lane & 7;
  float pacc = 0.f;
  float di = 0.f;
  if (node < n) {
    int s0 = offs[node], s1 = offs[node + 1];
    di = dinv[node];
    for (int e0 = s0; e0 < s1; e0 += 8) {
      int e = e0 + j8;
      if (e < s1) {
        int s = csr[e];
        pacc = fmaf(dinv[s], h[(size_t)s * 8 + f], pacc);
      }
    }
  }
  pacc += __shfl_down(pacc, 32);
  pacc += __shfl_down(pacc, 16);
  pacc += __shfl_down(pacc, 8);
  if (node < n && lane < 8) {
    float v = pacc + di * h[(size_t)node * 8 + f];
    sa[wv][f] = fmaxf(fmaf(di, v, b2[f]), 0.f);
  }
  __syncthreads();
  if (tid < 16) {
    int j = tid >> 2, ff = tid & 3;
    int nd = blockIdx.x * 4 + j;
    if (nd < n) {
      float s = 0.f;
#pragma unroll
      for (int k = 0; k < 8; ++k) s = fmaf(sa[j][k], w3s[k * 4 + ff], s);
      h3[(size_t)nd * 4 + ff] = s;
    }
  }
}

// ---------------- pull4 (h3 -> a3, relu+bias) ----------------
__global__ __launch_bounds__(256) void k_pull4(const float* __restrict__ h, const int* __restrict__ offs,
                                               const int* __restrict__ csr, const float* __restrict__ dinv,
                                               const float* __restrict__ b3, float* __restrict__ out, int n) {
  const int tid = threadIdx.x;
  const int lane = tid & 63;
  const int node = blockIdx.x * 4 + (tid >> 6);
  if (node >= n) return;
  const int j16 = lane >> 2, f = lane & 3;
  int s0 = offs[node], s1 = offs[node + 1];
  float di = dinv[node];
  float pacc = 0.f;
  for (int e0 = s0; e0 < s1; e0 += 16) {
    int e = e0 + j16;
    if (e < s1) {
      int s = csr[e];
      pacc = fmaf(dinv[s], h[(size_t)s * 4 + f], pacc);
    }
  }
  pacc += __shfl_down(pacc, 32);
  pacc += __shfl_down(pacc, 16);
  pacc += __shfl_down(pacc, 8);
  pacc += __shfl_down(pacc, 4);
  if (lane < 4) {
    float v = pacc + di * h[(size_t)node * 4 + f];
    out[(size_t)node * 4 + f] = fmaxf(fmaf(di, v, b3[f]), 0.f);
  }
}

// ---------------- final pull4 + fused mu/lv heads ----------------
__global__ __launch_bounds__(256) void k_pull4o(const float* __restrict__ a3, const int* __restrict__ offs,
                                                const int* __restrict__ csr, const float* __restrict__ dinv,
                                                const float* __restrict__ Wmu, const float* __restrict__ bmu,
                                                const float* __restrict__ Wlv, const float* __restrict__ blv,
                                                float* __restrict__ outp, int n) {
  __shared__ float sg[4][4];
  const int tid = threadIdx.x;
  const int lane = tid & 63;
  const int wv = tid >> 6;
  const int node = blockIdx.x * 4 + wv;
  const int j16 = lane >> 2, f = lane & 3;
  float pacc = 0.f;
  float di = 0.f;
  if (node < n) {
    int s0 = offs[node], s1 = offs[node + 1];
    di = dinv[node];
    for (int e0 = s0; e0 < s1; e0 += 16) {
      int e = e0 + j16;
      if (e < s1) {
        int s = csr[e];
        pacc = fmaf(dinv[s], a3[(size_t)s * 4 + f], pacc);
      }
    }
  }
  pacc += __shfl_down(pacc, 32);
  pacc += __shfl_down(pacc, 16);
  pacc += __shfl_down(pacc, 8);
  pacc += __shfl_down(pacc, 4);
  if (node < n && lane < 4) {
    float v = pacc + di * a3[(size_t)node * 4 + f];
    sg[wv][f] = di * v;
  }
  __syncthreads();
  if (tid < 16) {
    int j = tid >> 2, c = tid & 3;  // c: 0=mu0 1=mu1 2=lv0 3=lv1
    int nd = blockIdx.x * 4 + j;
    if (nd < n) {
      const float* Wp = (c < 2) ? Wmu : Wlv;
      const float* bp = (c < 2) ? bmu : blv;
      int cc = c & 1;
      float s = bp[cc];
#pragma unroll
      for (int k = 0; k < 4; ++k) s = fmaf(sg[j][k], Wp[k * 2 + cc], s);
      size_t base = (c < 2) ? 0 : (size_t)2 * n;
      outp[base + (size_t)nd * 2 + cc] = s;
    }
  }
}

extern "C" void kernel_launch(void* const* d_in, const int* in_sizes, int n_in,
                              void* d_out, int out_size, void* d_ws, size_t ws_size,
                              hipStream_t stream) {
  const float* x = (const float*)d_in[0];
  const int* ei = (const int*)d_in[1];
  const float* W1 = (const float*)d_in[2];
  const float* b1 = (const float*)d_in[3];
  const float* W2 = (const float*)d_in[4];
  const float* b2 = (const float*)d_in[5];
  const float* W3 = (const float*)d_in[6];
  const float* b3 = (const float*)d_in[7];
  const float* Wmu = (const float*)d_in[8];
  const float* bmu = (const float*)d_in[9];
  const float* Wlv = (const float*)d_in[10];
  const float* blv = (const float*)d_in[11];
  float* out = (float*)d_out;

  const int N = in_sizes[0] / 512;
  const int E = in_sizes[1] / 2;
  const int* esrc = ei;
  const int* edst = ei + E;
  const int NB = (N + BPB - 1) >> BSHIFT;  // 782

  char* w = (char*)d_ws;
  size_t p = 0;
  auto alloc = [&](size_t bytes) -> void* {
    void* r = w + p;
    p = (p + bytes + 255) & ~(size_t)255;
    return r;
  };
  int* bcnt = (int*)alloc((size_t)NB * 16 * 4);  // 64B-padded counters
  int* bbase = (int*)alloc((size_t)NB * 4);
  int* offs = (int*)alloc((size_t)(N + 1) * 4);
  float* dinv = (float*)alloc((size_t)N * 4);
  int* csr = (int*)alloc((size_t)E * 4);
  int* pairs = (int*)alloc((size_t)NB * CAP * 4);
  __half* h1 = (__half*)alloc((size_t)N * 64 * 2);
  float* h2 = (float*)alloc((size_t)N * 8 * 4);
  float* h3 = (float*)alloc((size_t)N * 4 * 4);
  float* a3 = (float*)alloc((size_t)N * 4 * 4);

  hipMemsetAsync(bcnt, 0, (size_t)NB * 16 * 4, stream);

  const int Gg = (N + 127) / 128;
  const int Gp = (E + 255) / 256;
  k_gp<<<Gg + Gp, 256, 0, stream>>>(x, W1, h1, N, Gg, esrc, edst, bcnt, pairs, E);
  k_bscan<<<1, 1024, 0, stream>>>(bcnt, bbase, offs, NB, N, E);
  k_p2<<<NB, 1024, 0, stream>>>(pairs, bcnt, bbase, offs, dinv, csr, N);

  k_pull64<<<(N + 3) / 4, 256, 0, stream>>>(h1, offs, csr, dinv, b1, W2, h2, N);
  k_pull8<<<(N + 3) / 4, 256, 0, stream>>>(h2, offs, csr, dinv, b2, W3, h3, N);
  k_pull4<<<(N + 3) / 4, 256, 0, stream>>>(h3, offs, csr, dinv, b3, a3, N);
  k_pull4o<<<(N + 3) / 4, 256, 0, stream>>>(a3, offs, csr, dinv, Wmu, bmu, Wlv, blv, out, N);
}

// Round 5
// 651.815 us; speedup vs baseline: 1.8291x; 1.0711x over previous
//
#include <hip/hip_runtime.h>
#include <hip/hip_fp16.h>
#include <stdint.h>

// VGAE GCN encoder. CSR build via LDS-binned 2-phase bucket partition:
//   k_part: edges -> 782 buckets (128 dst-nodes each); per-block LDS rings of 40
//     slots/bucket, flushed in full 64B groups of 16 -> ~1x write amplification
//     (R4 showed 16x amp: 4B frontier writes from 8 non-coherent XCD L2s).
//   k_bscan: 782-entry exclusive scan -> bucket bases; offs[N]=E.
//   k_p2: per bucket: LDS degree count (emits offs+dinv), LDS rank, coalesced csr.
// k_gemm1 (standalone; R4's fusion made 12.5K partition blocks hog gemm's LDS):
//   h1 = x@W1 fp16, XOR-swizzled x-tile (16B-aligned b128 reads + conflict-free
//   stores; R4's stride-133 pad broke b128 alignment -> 22.4M conflict cycles).
// Then: h2 = relu(pull64(h1)+b1)@W2 ; h3 = relu(pull8(h2)+b2)@W3 ;
//       a3 = relu(pull4(h3)+b3) ; [mu|lv] = pull4(a3)@[Wmu|Wlv]+bias.

#define BSHIFT 7
#define BPB 128           // nodes per bucket
#define CAP 5632          // slots per bucket in pairs (avg 4096 + 24 sigma)
#define NBMAX 800         // >= NB = 782
#define CAPB 40           // LDS ring slots per bin (carry<=15 + round max ~25: P~1e-17)

// ---------------- partition: edges -> bucketed pairs ----------------
__global__ __launch_bounds__(1024) void k_part(const int* __restrict__ esrc, const int* __restrict__ edst,
                                               int* __restrict__ bcnt, int* __restrict__ pairs,
                                               int E, int NB, int nblocks) {
  __shared__ int bincnt[NBMAX];
  __shared__ int sflushed[NBMAX];
  __shared__ int binbuf[NBMAX * CAPB];
  const int tid = threadIdx.x;
  for (int b = tid; b < NB; b += 1024) { bincnt[b] = 0; sflushed[b] = 0; }
  __syncthreads();
  const int chunk = (E + nblocks - 1) / nblocks;
  const int e0 = blockIdx.x * chunk;
  const int e1 = min(e0 + chunk, E);
  for (int base = e0; base < e1; base += 1024) {
    int e = base + tid;
    if (e < e1) {
      int d = edst[e], s = esrc[e];
      int b = d >> BSHIFT;
      int pos = atomicAdd(&bincnt[b], 1);
      binbuf[b * CAPB + (pos % CAPB)] = (s << BSHIFT) | (d & (BPB - 1));
    }
    __syncthreads();
    if (tid < NB) {
      int c = bincnt[tid], f = sflushed[tid];
      while (c - f >= 16) {  // flush full 64B lines only
        int p = atomicAdd(&bcnt[tid * 16], 16);
#pragma unroll
        for (int j = 0; j < 16; ++j)
          pairs[(size_t)tid * CAP + p + j] = binbuf[tid * CAPB + ((f + j) % CAPB)];
        f += 16;
      }
      sflushed[tid] = f;
    }
    __syncthreads();
  }
  if (tid < NB) {  // drain partial lines (<=1 per bin per block)
    int c = bincnt[tid], f = sflushed[tid];
    int rem = c - f;
    if (rem > 0) {
      int p = atomicAdd(&bcnt[tid * 16], rem);
      for (int j = 0; j < rem; ++j)
        pairs[(size_t)tid * CAP + p + j] = binbuf[tid * CAPB + ((f + j) % CAPB)];
    }
  }
}

// ---------------- GEMM1: h1[n][64] = x[n][512] @ W1[512][64], fp16 out --------
// 256 thr = 128 nodes x 64 feats; thread: 4 nodes x 8 feats (acc[32]).
// xs XOR swizzle: word(k,node) = k*128 + (node ^ 8*((k>>2)&3)).
//   reads : float4 over nodes, 16B-aligned, words 0..127 permuted -> conflict-free
//   stores: bank = lrl + 8*(w ^ (lc&3)) -> all 32 banks, 2-way (free)
__global__ __launch_bounds__(256, 4) void k_gemm1(const float* __restrict__ x, const float* __restrict__ W,
                                                  __half* __restrict__ h1, int n) {
  __shared__ float xs[32 * 128];
  __shared__ float ws[32 * 64];
  const int tid = threadIdx.x;
  const int n0 = blockIdx.x * 128;
  const int tn = tid & 31;  // nodes tn*4 .. +3
  const int tf = tid >> 5;  // feats tf*8 .. +7
  const int lr = tid >> 3;  // 0..31
  const int lc = tid & 7;   // 0..7

  float4 px[4], pw[2];
  auto ldg_tile = [&](int kt) {
#pragma unroll
    for (int i = 0; i < 4; ++i) {
      int r = n0 + lr + i * 32;
      if (r >= n) r = n - 1;
      px[i] = *(const float4*)(x + (size_t)r * 512 + kt + lc * 4);
    }
#pragma unroll
    for (int i = 0; i < 2; ++i) {
      int idx = tid + 256 * i;
      int k = idx >> 4, f4 = idx & 15;
      pw[i] = *(const float4*)(W + (size_t)(kt + k) * 64 + f4 * 4);
    }
  };

  float acc[4][8];
#pragma unroll
  for (int i = 0; i < 4; ++i)
#pragma unroll
    for (int j = 0; j < 8; ++j) acc[i][j] = 0.f;

  ldg_tile(0);
  for (int t = 0; t < 16; ++t) {
    __syncthreads();
    {
      const int sw = 8 * (lc & 3);  // (k>>2)&3 == lc&3 for k = lc*4+j
#pragma unroll
      for (int i = 0; i < 4; ++i) {
        int r = (lr + i * 32) ^ sw;
        xs[(lc * 4 + 0) * 128 + r] = px[i].x;
        xs[(lc * 4 + 1) * 128 + r] = px[i].y;
        xs[(lc * 4 + 2) * 128 + r] = px[i].z;
        xs[(lc * 4 + 3) * 128 + r] = px[i].w;
      }
#pragma unroll
      for (int i = 0; i < 2; ++i) {
        int idx = tid + 256 * i;
        *(float4*)&ws[(idx >> 4) * 64 + (idx & 15) * 4] = pw[i];
      }
    }
    __syncthreads();
    if (t < 15) ldg_tile((t + 1) * 32);  // prefetch hides under MACs
#pragma unroll 8
    for (int k = 0; k < 32; ++k) {
      float4 xv = *(const float4*)&xs[k * 128 + ((tn * 4) ^ (8 * ((k >> 2) & 3)))];
      float4 w0 = *(const float4*)&ws[k * 64 + tf * 8];
      float4 w1 = *(const float4*)&ws[k * 64 + tf * 8 + 4];
      float xa[4] = {xv.x, xv.y, xv.z, xv.w};
      float wb[8] = {w0.x, w0.y, w0.z, w0.w, w1.x, w1.y, w1.z, w1.w};
#pragma unroll
      for (int i = 0; i < 4; ++i)
#pragma unroll
        for (int j = 0; j < 8; ++j) acc[i][j] = fmaf(xa[i], wb[j], acc[i][j]);
    }
  }
#pragma unroll
  for (int i = 0; i < 4; ++i) {
    int node = n0 + tn * 4 + i;
    if (node < n) {
      union { int4 v; __half h[8]; } u;
#pragma unroll
      for (int j = 0; j < 8; ++j) u.h[j] = __float2half_rn(acc[i][j]);
      *(int4*)(h1 + (size_t)node * 64 + tf * 8) = u.v;
    }
  }
}

// ---------------- bucket-size scan (one block) ----------------
__global__ __launch_bounds__(1024) void k_bscan(const int* __restrict__ bcnt, int* __restrict__ bbase,
                                                int* __restrict__ offs, int NB, int n, int E) {
  __shared__ int sc[1024];
  int tid = threadIdx.x;
  int v = (tid < NB) ? bcnt[tid * 16] : 0;
  sc[tid] = v;
  __syncthreads();
  for (int d = 1; d < 1024; d <<= 1) {
    int t = (tid >= d) ? sc[tid - d] : 0;
    __syncthreads();
    if (tid >= d) sc[tid] += t;
    __syncthreads();
  }
  if (tid < NB) bbase[tid] = sc[tid] - v;  // exclusive
  if (tid == 0) offs[n] = E;
}

// ---------------- per-bucket CSR finalize (also emits offs + dinv) -----------
__global__ __launch_bounds__(1024) void k_p2(const int* __restrict__ pairs, const int* __restrict__ bcnt,
                                             const int* __restrict__ bbase, int* __restrict__ offs,
                                             float* __restrict__ dinv, int* __restrict__ csr, int n) {
  __shared__ int lcnt[BPB];
  __shared__ int scanv[BPB];
  __shared__ int cur[BPB];
  __shared__ int sbuf[CAP];
  const int tid = threadIdx.x;
  const int b = blockIdx.x;
  const int size = bcnt[b * 16];
  const int base = bbase[b];
  const int node0 = b << BSHIFT;
  const int nb = min(BPB, n - node0);

  if (tid < BPB) lcnt[tid] = 0;
  __syncthreads();

  int stash[6];
  int ns = 0;
  for (int i = tid; i < size; i += 1024) {
    int w = pairs[(size_t)b * CAP + i];
    stash[ns++] = w;
    atomicAdd(&lcnt[w & (BPB - 1)], 1);
  }
  __syncthreads();
  if (tid < BPB) scanv[tid] = lcnt[tid];
  __syncthreads();
#pragma unroll
  for (int d = 1; d < BPB; d <<= 1) {
    int t = (tid < BPB && tid >= d) ? scanv[tid - d] : 0;
    __syncthreads();
    if (tid < BPB && tid >= d) scanv[tid] += t;
    __syncthreads();
  }
  if (tid < nb) {
    int excl = scanv[tid] - lcnt[tid];
    offs[node0 + tid] = base + excl;
    cur[tid] = excl;
    dinv[node0 + tid] = rsqrtf((float)(lcnt[tid] + 1));  // +1 self-loop
  }
  __syncthreads();
  for (int i = 0; i < ns; ++i) {
    int w = stash[i];
    int p = atomicAdd(&cur[w & (BPB - 1)], 1);
    sbuf[p] = w >> BSHIFT;
  }
  __syncthreads();
  for (int i = tid; i < size; i += 1024) csr[base + i] = sbuf[i];
}

// ---------------- pull64 (fp16 gather) + fused gemm2 ----------------
__global__ __launch_bounds__(256) void k_pull64(const __half* __restrict__ h, const int* __restrict__ offs,
                                                const int* __restrict__ csr, const float* __restrict__ dinv,
                                                const float* __restrict__ b1, const float* __restrict__ W2,
                                                float* __restrict__ h2, int n) {
  __shared__ float sa[4][64];
  __shared__ float w2s[512];
  const int tid = threadIdx.x;
  w2s[tid] = W2[tid];
  w2s[tid + 256] = W2[tid + 256];
  const int lane = tid & 63;
  const int wv = tid >> 6;
  const int node = blockIdx.x * 4 + wv;
  float a1v = 0.f;
  if (node < n) {
    int s0 = offs[node], s1 = offs[node + 1];
    float di = dinv[node];
    float acc = 0.f;
    int e = s0;
    for (; e + 4 <= s1; e += 4) {
      int i0 = csr[e], i1 = csr[e + 1], i2 = csr[e + 2], i3 = csr[e + 3];
      float w0 = dinv[i0], w1 = dinv[i1], w2 = dinv[i2], w3 = dinv[i3];
      float v0 = __half2float(h[(size_t)i0 * 64 + lane]);
      float v1 = __half2float(h[(size_t)i1 * 64 + lane]);
      float v2 = __half2float(h[(size_t)i2 * 64 + lane]);
      float v3 = __half2float(h[(size_t)i3 * 64 + lane]);
      acc = fmaf(w0, v0, acc); acc = fmaf(w1, v1, acc);
      acc = fmaf(w2, v2, acc); acc = fmaf(w3, v3, acc);
    }
    for (; e < s1; ++e) {
      int s = csr[e];
      acc = fmaf(dinv[s], __half2float(h[(size_t)s * 64 + lane]), acc);
    }
    acc = fmaf(di, __half2float(h[(size_t)node * 64 + lane]), acc);  // self-loop
    a1v = fmaxf(fmaf(di, acc, b1[lane]), 0.f);
  }
  sa[wv][lane] = a1v;
  __syncthreads();
  if (tid < 32) {
    int j = tid >> 3, f = tid & 7;
    int nd = blockIdx.x * 4 + j;
    if (nd < n) {
      float s = 0.f;
#pragma unroll
      for (int l = 0; l < 64; ++l) s = fmaf(sa[j][l], w2s[l * 8 + f], s);
      h2[(size_t)nd * 8 + f] = s;
    }
  }
}

// ---------------- pull8 + fused gemm3 ----------------
__global__ __launch_bounds__(256) void k_pull8(const float* __restrict__ h, const int* __restrict__ offs,
                                               const int* __restrict__ csr, const float* __restrict__ dinv,
                                               const float* __restrict__ b2, const float* __restrict__ W3,
                                               float* __restrict__ h3, int n) {
  __shared__ float sa[4][8];
  __shared__ float w3s[32];
  const int tid = threadIdx.x;
  if (tid < 32) w3s[tid] = W3[tid];
  const int lane = tid & 63;
  const int wv = tid >> 6;
  const int node = blockIdx.x * 4 + wv;
  const int j8 = lane >> 3, f = lane & 7;
  float pacc = 0.f;
  float di = 0.f;
  if (node < n) {
    int s0 = offs[node], s1 = offs[node + 1];
    di = dinv[node];
    for (int e0 = s0; e0 < s1; e0 += 8) {
      int e = e0 + j8;
      if (e < s1) {
        int s = csr[e];
        pacc = fmaf(dinv[s], h[(size_t)s * 8 + f], pacc);
      }
    }
  }
  pacc += __shfl_down(pacc, 32);
  pacc += __shfl_down(pacc, 16);
  pacc += __shfl_down(pacc, 8);
  if (node < n && lane < 8) {
    float v = pacc + di * h[(size_t)node * 8 + f];
    sa[wv][f] = fmaxf(fmaf(di, v, b2[f]), 0.f);
  }
  __syncthreads();
  if (tid < 16) {
    int j = tid >> 2, ff = tid & 3;
    int nd = blockIdx.x * 4 + j;
    if (nd < n) {
      float s = 0.f;
#pragma unroll
      for (int k = 0; k < 8; ++k) s = fmaf(sa[j][k], w3s[k * 4 + ff], s);
      h3[(size_t)nd * 4 + ff] = s;
    }
  }
}

// ---------------- pull4 (h3 -> a3, relu+bias) ----------------
__global__ __launch_bounds__(256) void k_pull4(const float* __restrict__ h, const int* __restrict__ offs,
                                               const int* __restrict__ csr, const float* __restrict__ dinv,
                                               const float* __restrict__ b3, float* __restrict__ out, int n) {
  const int tid = threadIdx.x;
  const int lane = tid & 63;
  const int node = blockIdx.x * 4 + (tid >> 6);
  if (node >= n) return;
  const int j16 = lane >> 2, f = lane & 3;
  int s0 = offs[node], s1 = offs[node + 1];
  float di = dinv[node];
  float pacc = 0.f;
  for (int e0 = s0; e0 < s1; e0 += 16) {
    int e = e0 + j16;
    if (e < s1) {
      int s = csr[e];
      pacc = fmaf(dinv[s], h[(size_t)s * 4 + f], pacc);
    }
  }
  pacc += __shfl_down(pacc, 32);
  pacc += __shfl_down(pacc, 16);
  pacc += __shfl_down(pacc, 8);
  pacc += __shfl_down(pacc, 4);
  if (lane < 4) {
    float v = pacc + di * h[(size_t)node * 4 + f];
    out[(size_t)node * 4 + f] = fmaxf(fmaf(di, v, b3[f]), 0.f);
  }
}

// ---------------- final pull4 + fused mu/lv heads ----------------
__global__ __launch_bounds__(256) void k_pull4o(const float* __restrict__ a3, const int* __restrict__ offs,
                                                const int* __restrict__ csr, const float* __restrict__ dinv,
                                                const float* __restrict__ Wmu, const float* __restrict__ bmu,
                                                const float* __restrict__ Wlv, const float* __restrict__ blv,
                                                float* __restrict__ outp, int n) {
  __shared__ float sg[4][4];
  const int tid = threadIdx.x;
  const int lane = tid & 63;
  const int wv = tid >> 6;
  const int node = blockIdx.x * 4 + wv;
  const int j16 = lane >> 2, f = lane & 3;
  float pacc = 0.f;
  float di = 0.f;
  if (node < n) {
    int s0 = offs[node], s1 = offs[node + 1];
    di = dinv[node];
    for (int e0 = s0; e0 < s1; e0 += 16) {
      int e = e0 + j16;
      if (e < s1) {
        int s = csr[e];
        pacc = fmaf(dinv[s], a3[(size_t)s * 4 + f], pacc);
      }
    }
  }
  pacc += __shfl_down(pacc, 32);
  pacc += __shfl_down(pacc, 16);
  pacc += __shfl_down(pacc, 8);
  pacc += __shfl_down(pacc, 4);
  if (node < n && lane < 4) {
    float v = pacc + di * a3[(size_t)node * 4 + f];
    sg[wv][f] = di * v;
  }
  __syncthreads();
  if (tid < 16) {
    int j = tid >> 2, c = tid & 3;  // c: 0=mu0 1=mu1 2=lv0 3=lv1
    int nd = blockIdx.x * 4 + j;
    if (nd < n) {
      const float* Wp = (c < 2) ? Wmu : Wlv;
      const float* bp = (c < 2) ? bmu : blv;
      int cc = c & 1;
      float s = bp[cc];
#pragma unroll
      for (int k = 0; k < 4; ++k) s = fmaf(sg[j][k], Wp[k * 2 + cc], s);
      size_t base = (c < 2) ? 0 : (size_t)2 * n;
      outp[base + (size_t)nd * 2 + cc] = s;
    }
  }
}

extern "C" void kernel_launch(void* const* d_in, const int* in_sizes, int n_in,
                              void* d_out, int out_size, void* d_ws, size_t ws_size,
                              hipStream_t stream) {
  const float* x = (const float*)d_in[0];
  const int* ei = (const int*)d_in[1];
  const float* W1 = (const float*)d_in[2];
  const float* b1 = (const float*)d_in[3];
  const float* W2 = (const float*)d_in[4];
  const float* b2 = (const float*)d_in[5];
  const float* W3 = (const float*)d_in[6];
  const float* b3 = (const float*)d_in[7];
  const float* Wmu = (const float*)d_in[8];
  const float* bmu = (const float*)d_in[9];
  const float* Wlv = (const float*)d_in[10];
  const float* blv = (const float*)d_in[11];
  float* out = (float*)d_out;

  const int N = in_sizes[0] / 512;
  const int E = in_sizes[1] / 2;
  const int* esrc = ei;
  const int* edst = ei + E;
  const int NB = (N + BPB - 1) >> BSHIFT;  // 782

  char* w = (char*)d_ws;
  size_t p = 0;
  auto alloc = [&](size_t bytes) -> void* {
    void* r = w + p;
    p = (p + bytes + 255) & ~(size_t)255;
    return r;
  };
  int* bcnt = (int*)alloc((size_t)NB * 16 * 4);  // 64B-padded counters
  int* bbase = (int*)alloc((size_t)NB * 4);
  int* offs = (int*)alloc((size_t)(N + 1) * 4);
  float* dinv = (float*)alloc((size_t)N * 4);
  int* csr = (int*)alloc((size_t)E * 4);
  int* pairs = (int*)alloc((size_t)NB * CAP * 4);
  __half* h1 = (__half*)alloc((size_t)N * 64 * 2);
  float* h2 = (float*)alloc((size_t)N * 8 * 4);
  float* h3 = (float*)alloc((size_t)N * 4 * 4);
  float* a3 = (float*)alloc((size_t)N * 4 * 4);

  hipMemsetAsync(bcnt, 0, (size_t)NB * 16 * 4, stream);

  k_part<<<256, 1024, 0, stream>>>(esrc, edst, bcnt, pairs, E, NB, 256);
  k_gemm1<<<(N + 127) / 128, 256, 0, stream>>>(x, W1, h1, N);
  k_bscan<<<1, 1024, 0, stream>>>(bcnt, bbase, offs, NB, N, E);
  k_p2<<<NB, 1024, 0, stream>>>(pairs, bcnt, bbase, offs, dinv, csr, N);

  k_pull64<<<(N + 3) / 4, 256, 0, stream>>>(h1, offs, csr, dinv, b1, W2, h2, N);
  k_pull8<<<(N + 3) / 4, 256, 0, stream>>>(h2, offs, csr, dinv, b2, W3, h3, N);
  k_pull4<<<(N + 3) / 4, 256, 0, stream>>>(h3, offs, csr, dinv, b3, a3, N);
  k_pull4o<<<(N + 3) / 4, 256, 0, stream>>>(a3, offs, csr, dinv, Wmu, bmu, Wlv, blv, out, N);
}